// Round 16
// baseline (299.246 us; speedup 1.0000x reference)
//
#include <hip/hip_runtime.h>
#include <math.h>

#define N_NODES 50000
#define N_EDGES 800000
#define TPB 256
#define NCHUNK ((N_NODES + 255) / 256)   // 196 scan blocks

typedef short s16x8 __attribute__((ext_vector_type(8)));
typedef float f32x4 __attribute__((ext_vector_type(4)));

__device__ __forceinline__ unsigned short f2bf(float f) {
    unsigned u = __float_as_uint(f);
    u += 0x7fffu + ((u >> 16) & 1u);          // round-to-nearest-even
    return (unsigned short)(u >> 16);
}
__device__ __forceinline__ float bf2f(unsigned short h) {
    return __uint_as_float(((unsigned)h) << 16);
}

// ---------------- weight transposes + bf16 cast + deg zero, one launch ----------------
__global__ void wt_all_k(const float* __restrict__ s1Wl, const float* __restrict__ s1Wr,
                         const float* __restrict__ gW, const float* __restrict__ s2Wl,
                         const float* __restrict__ s2Wr, unsigned short* __restrict__ Wt1,
                         unsigned short* __restrict__ Wt2, unsigned short* __restrict__ Wt3,
                         int* __restrict__ deg) {
    int idx = blockIdx.x * TPB + threadIdx.x;
    if (idx < N_NODES) deg[idx] = 0;
    if (idx < 16384) {                       // 256*64
        int n = idx >> 6, k = idx & 63;
        float v = 0.f;
        if (k < 20) v = s1Wl[k * 256 + n];
        else if (k < 40) v = s1Wr[(k - 20) * 256 + n];
        Wt1[idx] = f2bf(v);
    } else if (idx < 49152) {                // + 128*256
        int j = idx - 16384;
        int n = j >> 8, k = j & 255;
        Wt2[j] = f2bf(gW[(size_t)k * 128 + n]);
    } else if (idx < 114688) {               // + 256*256
        int j = idx - 49152;
        int n = j >> 8, k = j & 255;
        float v = (k < 128) ? s2Wl[(size_t)k * 256 + n] : s2Wr[(size_t)(k - 128) * 256 + n];
        Wt3[j] = f2bf(v);
    }
}

// ---------------- bf16 MFMA GEMM, f32 A inputs (SAGE1) ----------------
template<int ACT>
__global__ void gemm_mfma(const float* __restrict__ A1, int K1,
                          const float* __restrict__ A2, int K2,
                          const unsigned short* __restrict__ Wt, int Kp,
                          const float* __restrict__ bias,
                          unsigned short* __restrict__ outb, int NO) {
    constexpr int BM = 128, BK = 32, LDP = 40;
    __shared__ unsigned short sA[BM * LDP];
    __shared__ unsigned short sB[128 * LDP];
    const int K = K1 + K2;
    const int T = Kp / BK;
    const int tid = threadIdx.x;
    const int lane = tid & 63, wid = tid >> 6;
    const int wr = wid >> 1, wc = wid & 1;
    const int row0 = blockIdx.y * BM, col0 = blockIdx.x * 128;
    const int l15 = lane & 15, l4 = lane >> 4;
    f32x4 acc[4][4] = {};

    for (int t = 0; t < T; ++t) {
        __syncthreads();
#pragma unroll
        for (int j = 0; j < 4; ++j) {
            int e = tid + j * 256;
            int r = e >> 3, k4 = e & 7;
            int kg = t * BK + k4 * 4, mg = row0 + r;
            float4 v = {0.f, 0.f, 0.f, 0.f};
            if (mg < N_NODES) {
                if (kg < K1)     v = *(const float4*)&A1[(size_t)mg * K1 + kg];
                else if (kg < K) v = *(const float4*)&A2[(size_t)mg * K2 + (kg - K1)];
            }
            ushort4 b;
            b.x = f2bf(v.x); b.y = f2bf(v.y); b.z = f2bf(v.z); b.w = f2bf(v.w);
            *(ushort4*)&sA[r * LDP + k4 * 4] = b;
        }
#pragma unroll
        for (int j = 0; j < 2; ++j) {
            int e = tid + j * 256;
            int n = e >> 2, k8 = e & 3;
            int4 v = *(const int4*)&Wt[(size_t)(col0 + n) * Kp + t * BK + k8 * 8];
            *(int4*)&sB[n * LDP + k8 * 8] = v;
        }
        __syncthreads();
        s16x8 af[4], bfr[4];
#pragma unroll
        for (int i = 0; i < 4; ++i) {
            af[i]  = *(const s16x8*)&sA[(wr * 64 + i * 16 + l15) * LDP + l4 * 8];
            bfr[i] = *(const s16x8*)&sB[(wc * 64 + i * 16 + l15) * LDP + l4 * 8];
        }
#pragma unroll
        for (int mi = 0; mi < 4; ++mi)
#pragma unroll
            for (int ni = 0; ni < 4; ++ni)
                acc[mi][ni] = __builtin_amdgcn_mfma_f32_16x16x32_bf16(
                    af[mi], bfr[ni], acc[mi][ni], 0, 0, 0);
    }
#pragma unroll
    for (int mi = 0; mi < 4; ++mi) {
#pragma unroll
        for (int ni = 0; ni < 4; ++ni) {
            int col = col0 + wc * 64 + ni * 16 + l15;
            float bb = bias ? bias[col] : 0.f;
#pragma unroll
            for (int r = 0; r < 4; ++r) {
                int row = row0 + wr * 64 + mi * 16 + l4 * 4 + r;
                if (row < N_NODES) {
                    float v = acc[mi][ni][r] + bb;
                    if (ACT) v = fmaxf(v, 0.f);
                    outb[(size_t)row * NO + col] = f2bf(v);
                }
            }
        }
    }
}

// ---------------- bf16 MFMA GEMM, bf16 A inputs (GAT / SAGE2+cls-fused) ----------------
// CLS=1: skip h3 store entirely; compute per-block classifier partials into
// pp[blockIdx.x][n][5] (relu + bias folded). Deterministic (shfl + LDS planes).
template<int ACT, int CLS>
__global__ void gemm_mfma_bf(const unsigned short* __restrict__ A1, int K1,
                             const unsigned short* __restrict__ A2, int K2,
                             const unsigned short* __restrict__ Wt, int Kp,
                             const float* __restrict__ bias,
                             unsigned short* __restrict__ outb, int NO,
                             const float* __restrict__ clsW, float* __restrict__ pp) {
    constexpr int BM = 128, BK = 32, LDP = 40;
    __shared__ unsigned short sA[BM * LDP];    // 10240 B (aliased by sClsW in CLS epi)
    __shared__ unsigned short sB[128 * LDP];   // 10240 B (aliased by cp in CLS epi)
    const int T = Kp / BK;
    const int tid = threadIdx.x;
    const int lane = tid & 63, wid = tid >> 6;
    const int wr = wid >> 1, wc = wid & 1;
    const int row0 = blockIdx.y * BM, col0 = blockIdx.x * 128;
    const int l15 = lane & 15, l4 = lane >> 4;
    f32x4 acc[4][4] = {};

    for (int t = 0; t < T; ++t) {
        __syncthreads();
#pragma unroll
        for (int j = 0; j < 2; ++j) {
            int e = tid + j * 256;
            int r = e >> 2, k8 = e & 3;
            int kg = t * BK + k8 * 8, mg = row0 + r;
            int4 v = {0, 0, 0, 0};
            if (mg < N_NODES) {
                if (kg < K1) v = *(const int4*)&A1[(size_t)mg * K1 + kg];
                else         v = *(const int4*)&A2[(size_t)mg * K2 + (kg - K1)];
            }
            *(int4*)&sA[r * LDP + k8 * 8] = v;
        }
#pragma unroll
        for (int j = 0; j < 2; ++j) {
            int e = tid + j * 256;
            int n = e >> 2, k8 = e & 3;
            int4 v = *(const int4*)&Wt[(size_t)(col0 + n) * Kp + t * BK + k8 * 8];
            *(int4*)&sB[n * LDP + k8 * 8] = v;
        }
        __syncthreads();
        s16x8 af[4], bfr[4];
#pragma unroll
        for (int i = 0; i < 4; ++i) {
            af[i]  = *(const s16x8*)&sA[(wr * 64 + i * 16 + l15) * LDP + l4 * 8];
            bfr[i] = *(const s16x8*)&sB[(wc * 64 + i * 16 + l15) * LDP + l4 * 8];
        }
#pragma unroll
        for (int mi = 0; mi < 4; ++mi)
#pragma unroll
            for (int ni = 0; ni < 4; ++ni)
                acc[mi][ni] = __builtin_amdgcn_mfma_f32_16x16x32_bf16(
                    af[mi], bfr[ni], acc[mi][ni], 0, 0, 0);
    }

    if (CLS == 0) {
#pragma unroll
        for (int mi = 0; mi < 4; ++mi) {
#pragma unroll
            for (int ni = 0; ni < 4; ++ni) {
                int col = col0 + wc * 64 + ni * 16 + l15;
                float bb = bias ? bias[col] : 0.f;
#pragma unroll
                for (int r = 0; r < 4; ++r) {
                    int row = row0 + wr * 64 + mi * 16 + l4 * 4 + r;
                    if (row < N_NODES) {
                        float v = acc[mi][ni][r] + bb;
                        if (ACT) v = fmaxf(v, 0.f);
                        outb[(size_t)row * NO + col] = f2bf(v);
                    }
                }
            }
        }
    } else {
        __syncthreads();                      // all LDS reads of last tile done
        float* sClsW = (float*)sA;            // 640 floats
        float* cp    = (float*)sB;            // 2 planes x 128 x 5 floats
        for (int i = tid; i < 640; i += 256)
            sClsW[i] = clsW[(size_t)(col0 + i / 5) * 5 + (i % 5)];
        __syncthreads();
        float bcol[4];
#pragma unroll
        for (int ni = 0; ni < 4; ++ni)
            bcol[ni] = bias[col0 + wc * 64 + ni * 16 + l15];
#pragma unroll
        for (int mi = 0; mi < 4; ++mi) {
#pragma unroll
            for (int r = 0; r < 4; ++r) {
                float p0 = 0.f, p1 = 0.f, p2 = 0.f, p3 = 0.f, p4 = 0.f;
#pragma unroll
                for (int ni = 0; ni < 4; ++ni) {
                    float v = fmaxf(acc[mi][ni][r] + bcol[ni], 0.f);   // relu(h3)
                    const float* w = &sClsW[(wc * 64 + ni * 16 + l15) * 5];
                    p0 = fmaf(v, w[0], p0); p1 = fmaf(v, w[1], p1);
                    p2 = fmaf(v, w[2], p2); p3 = fmaf(v, w[3], p3);
                    p4 = fmaf(v, w[4], p4);
                }
#pragma unroll
                for (int msk = 1; msk < 16; msk <<= 1) {
                    p0 += __shfl_xor(p0, msk, 16);
                    p1 += __shfl_xor(p1, msk, 16);
                    p2 += __shfl_xor(p2, msk, 16);
                    p3 += __shfl_xor(p3, msk, 16);
                    p4 += __shfl_xor(p4, msk, 16);
                }
                if (l15 == 0) {
                    int rr = wr * 64 + mi * 16 + l4 * 4 + r;   // 0..127
                    float* d = &cp[(wc * 128 + rr) * 5];
                    d[0] = p0; d[1] = p1; d[2] = p2; d[3] = p3; d[4] = p4;
                }
            }
        }
        __syncthreads();
        for (int i = tid; i < 640; i += 256) {
            int rr = i / 5, cc = i - rr * 5;
            int row = row0 + rr;
            if (row < N_NODES)
                pp[(size_t)blockIdx.x * ((size_t)N_NODES * 5) + (size_t)row * 5 + cc]
                    = cp[rr * 5 + cc] + cp[(128 + rr) * 5 + cc];
        }
    }
}

// combine classifier partials: out = pp[0] + pp[1] + clsb
__global__ void combine_k(const float* __restrict__ pp, const float* __restrict__ clsb,
                          float* __restrict__ out) {
    int idx = blockIdx.x * TPB + threadIdx.x;
    if (idx >= N_NODES * 5) return;
    int c = idx % 5;
    out[idx] = pp[idx] + pp[(size_t)N_NODES * 5 + idx] + clsb[c];
}

// ---------------- CSR construction ----------------
__global__ void hist_k(const int* __restrict__ dst, int* __restrict__ deg) {
    int e = blockIdx.x * TPB + threadIdx.x;
    if (e < N_EDGES) atomicAdd(&deg[dst[e]], 1);
}

__global__ void scan1_k(const int* __restrict__ deg, int* __restrict__ rowptr,
                        int* __restrict__ bsum) {
    __shared__ int tmp[256];
    int tid = threadIdx.x;
    int idx = blockIdx.x * 256 + tid;
    int v = (idx < N_NODES) ? deg[idx] : 0;
    tmp[tid] = v;
    __syncthreads();
    for (int off = 1; off < 256; off <<= 1) {
        int t = (tid >= off) ? tmp[tid - off] : 0;
        __syncthreads();
        tmp[tid] += t;
        __syncthreads();
    }
    if (idx < N_NODES) rowptr[idx] = tmp[tid] - v;
    if (tid == 255) bsum[blockIdx.x] = tmp[255];
}

__global__ void scan2_k(int* __restrict__ bsum) {
    __shared__ int tmp[256];
    int tid = threadIdx.x;
    int v = (tid < NCHUNK) ? bsum[tid] : 0;
    tmp[tid] = v;
    __syncthreads();
    for (int off = 1; off < 256; off <<= 1) {
        int t = (tid >= off) ? tmp[tid - off] : 0;
        __syncthreads();
        tmp[tid] += t;
        __syncthreads();
    }
    if (tid < NCHUNK) bsum[tid] = tmp[tid] - v;
}

__global__ void scan3_k(int* __restrict__ rowptr, const int* __restrict__ bsum) {
    int idx = blockIdx.x * 256 + threadIdx.x;
    if (idx < N_NODES) rowptr[idx] += bsum[blockIdx.x];
    if (idx == 0) rowptr[N_NODES] = N_EDGES;
}

__global__ void fill_k(const int* __restrict__ src, const int* __restrict__ dst,
                       const int* __restrict__ rowptr, int* __restrict__ deg,
                       int* __restrict__ csr_src) {
    int e = blockIdx.x * TPB + threadIdx.x;
    if (e >= N_EDGES) return;
    int d = dst[e];
    int r = atomicSub(&deg[d], 1) - 1;
    csr_src[rowptr[d] + r] = src[e];
}

// ---------------- gather aggregations ----------------
// SAGE1 mean (F=20, f32): 32-lane group per node, 8 nodes per 256-block
__global__ void gm20_k(const int* __restrict__ rowptr, const int* __restrict__ csr_src,
                       const float* __restrict__ feat, float* __restrict__ out) {
    int tid = threadIdx.x;
    int n = blockIdx.x * 8 + (tid >> 5);
    int c = tid & 31;
    if (n >= N_NODES || c >= 20) return;
    int e0 = rowptr[n], e1 = rowptr[n + 1];
    float acc = 0.f;
    int e = e0;
    for (; e + 1 < e1; e += 2) {
        acc += feat[(size_t)csr_src[e] * 20 + c] + feat[(size_t)csr_src[e + 1] * 20 + c];
    }
    if (e < e1) acc += feat[(size_t)csr_src[e] * 20 + c];
    out[(size_t)n * 20 + c] = acc / fmaxf((float)(e1 - e0), 1.0f);
}

// bf16 mean for F=128: 32 lanes/node, 8 nodes/block, 8-edge unroll
__global__ void gather_mean_bf(const int* __restrict__ rowptr, const int* __restrict__ csr_src,
                               const unsigned short* __restrict__ featb,
                               unsigned short* __restrict__ outb) {
    int tid = threadIdx.x;
    int n = blockIdx.x * 8 + (tid >> 5);
    int c = tid & 31;
    int e0 = rowptr[n], e1 = rowptr[n + 1];
    float4 acc = {0.f, 0.f, 0.f, 0.f};
    int e = e0;
    for (; e + 7 < e1; e += 8) {
        ushort4 u[8];
#pragma unroll
        for (int j = 0; j < 8; ++j)
            u[j] = *(const ushort4*)&featb[(size_t)csr_src[e + j] * 128 + c * 4];
#pragma unroll
        for (int j = 0; j < 8; ++j) {
            acc.x += bf2f(u[j].x); acc.y += bf2f(u[j].y);
            acc.z += bf2f(u[j].z); acc.w += bf2f(u[j].w);
        }
    }
    for (; e < e1; ++e) {
        ushort4 u = *(const ushort4*)&featb[(size_t)csr_src[e] * 128 + c * 4];
        acc.x += bf2f(u.x); acc.y += bf2f(u.y); acc.z += bf2f(u.z); acc.w += bf2f(u.w);
    }
    float inv = 1.0f / fmaxf((float)(e1 - e0), 1.0f);
    ushort4 o;
    o.x = f2bf(acc.x * inv); o.y = f2bf(acc.y * inv);
    o.z = f2bf(acc.z * inv); o.w = f2bf(acc.w * inv);
    *(ushort4*)&outb[(size_t)n * 128 + c * 4] = o;
}

// per-(node,head) attention scores, bf16 h
__global__ void att_scores_bf(const unsigned short* __restrict__ hb,
                              const float* __restrict__ att_src,
                              const float* __restrict__ att_dst,
                              float* __restrict__ as_, float* __restrict__ ad_) {
    int idx = blockIdx.x * TPB + threadIdx.x;
    if (idx >= N_NODES * 4) return;
    int n = idx >> 2, hd = idx & 3;
    const unsigned short* row = hb + (size_t)n * 128 + hd * 32;
    float sa = 0.f, sd = 0.f;
#pragma unroll
    for (int c4 = 0; c4 < 8; ++c4) {
        ushort4 u = *(const ushort4*)&row[c4 * 4];
        const float* asr = &att_src[hd * 32 + c4 * 4];
        const float* adr = &att_dst[hd * 32 + c4 * 4];
        sa = fmaf(bf2f(u.x), asr[0], sa); sd = fmaf(bf2f(u.x), adr[0], sd);
        sa = fmaf(bf2f(u.y), asr[1], sa); sd = fmaf(bf2f(u.y), adr[1], sd);
        sa = fmaf(bf2f(u.z), asr[2], sa); sd = fmaf(bf2f(u.z), adr[2], sd);
        sa = fmaf(bf2f(u.w), asr[3], sa); sd = fmaf(bf2f(u.w), adr[3], sd);
    }
    as_[idx] = sa;
    ad_[idx] = sd;
}

// fused GAT aggregation: bf16 gather + online softmax with 8-lane-dedup'd
// score/exp work (lane q=c&7 computes edge e+q; shfl broadcast). ELU, bf16 out.
__global__ void gat_gather_bf(const int* __restrict__ rowptr, const int* __restrict__ csr_src,
                              const unsigned short* __restrict__ hb,
                              const float* __restrict__ as_, const float* __restrict__ ad_,
                              const float* __restrict__ gb,
                              unsigned short* __restrict__ outb) {
    int tid = threadIdx.x;
    int n = blockIdx.x * 8 + (tid >> 5);
    int c = tid & 31;              // float4 index within row; head = c>>3
    int hd = c >> 3;
    int q = c & 7;                 // sub-lane within 8-lane head group
    int e0 = rowptr[n], e1 = rowptr[n + 1];
    float ad = ad_[n * 4 + hd];
    float m = -INFINITY, s = 0.f;
    float4 acc = {0.f, 0.f, 0.f, 0.f};
    int e = e0;
    for (; e + 7 < e1; e += 8) {
        // own edge's score (per 8-lane head group: 1 as_ load + 1 exp per lane)
        int sq = csr_src[e + q];
        float aq = as_[sq * 4 + hd] + ad;
        aq = aq >= 0.f ? aq : 0.2f * aq;          // leaky_relu 0.2
        // group max over the 8 edges
        float pm = aq;
        pm = fmaxf(pm, __shfl_xor(pm, 1, 8));
        pm = fmaxf(pm, __shfl_xor(pm, 2, 8));
        pm = fmaxf(pm, __shfl_xor(pm, 4, 8));
        if (pm > m) {                              // one rescale per 8 edges
            float sc = __expf(m - pm);
            s *= sc; acc.x *= sc; acc.y *= sc; acc.z *= sc; acc.w *= sc;
            m = pm;
        }
        float exq = __expf(aq - m);
        float exs[8];
        int   sj[8];
#pragma unroll
        for (int j = 0; j < 8; ++j) {
            exs[j] = __shfl(exq, j, 8);
            sj[j]  = __shfl(sq, j, 8);
        }
        s += ((exs[0] + exs[1]) + (exs[2] + exs[3]))
           + ((exs[4] + exs[5]) + (exs[6] + exs[7]));
        ushort4 u[8];
#pragma unroll
        for (int j = 0; j < 8; ++j)
            u[j] = *(const ushort4*)&hb[(size_t)sj[j] * 128 + c * 4];
#pragma unroll
        for (int j = 0; j < 8; ++j) {
            float ex = exs[j];
            acc.x = fmaf(bf2f(u[j].x), ex, acc.x);
            acc.y = fmaf(bf2f(u[j].y), ex, acc.y);
            acc.z = fmaf(bf2f(u[j].z), ex, acc.z);
            acc.w = fmaf(bf2f(u[j].w), ex, acc.w);
        }
    }
    for (; e < e1; ++e) {                          // scalar tail (<8 edges)
        int s0 = csr_src[e];
        float a = as_[s0 * 4 + hd] + ad;
        a = a >= 0.f ? a : 0.2f * a;
        if (a > m) {
            float sc = __expf(m - a);
            s *= sc; acc.x *= sc; acc.y *= sc; acc.z *= sc; acc.w *= sc;
            m = a;
        }
        float ex = __expf(a - m);
        s += ex;
        ushort4 u = *(const ushort4*)&hb[(size_t)s0 * 128 + c * 4];
        acc.x = fmaf(bf2f(u.x), ex, acc.x); acc.y = fmaf(bf2f(u.y), ex, acc.y);
        acc.z = fmaf(bf2f(u.z), ex, acc.z); acc.w = fmaf(bf2f(u.w), ex, acc.w);
    }
    float inv = 1.0f / (s + 1e-16f);
    float rx = acc.x * inv + gb[c * 4 + 0];
    float ry = acc.y * inv + gb[c * 4 + 1];
    float rz = acc.z * inv + gb[c * 4 + 2];
    float rw = acc.w * inv + gb[c * 4 + 3];
    rx = rx > 0.f ? rx : expm1f(rx);
    ry = ry > 0.f ? ry : expm1f(ry);
    rz = rz > 0.f ? rz : expm1f(rz);
    rw = rw > 0.f ? rw : expm1f(rw);
    ushort4 o;
    o.x = f2bf(rx); o.y = f2bf(ry); o.z = f2bf(rz); o.w = f2bf(rw);
    *(ushort4*)&outb[(size_t)n * 128 + c * 4] = o;
}

extern "C" void kernel_launch(void* const* d_in, const int* in_sizes, int n_in,
                              void* d_out, int out_size, void* d_ws, size_t ws_size,
                              hipStream_t stream) {
    const float* x    = (const float*)d_in[0];
    const int*   ei   = (const int*)d_in[1];
    const float* s1Wl = (const float*)d_in[2];
    const float* s1Wr = (const float*)d_in[3];
    const float* s1b  = (const float*)d_in[4];
    const float* gW   = (const float*)d_in[5];
    const float* gas  = (const float*)d_in[6];
    const float* gad  = (const float*)d_in[7];
    const float* gb   = (const float*)d_in[8];
    const float* s2Wl = (const float*)d_in[9];
    const float* s2Wr = (const float*)d_in[10];
    const float* s2b  = (const float*)d_in[11];
    const float* clsW = (const float*)d_in[12];
    const float* clsb = (const float*)d_in[13];
    float* out = (float*)d_out;
    const int* src = ei;            // edge_index[0]
    const int* dst = ei + N_EDGES;  // edge_index[1]

    // ---- workspace layout (16B-aligned segments) ----
    float* ws  = (float*)d_ws;
    float* M20  = ws;                                 // N*20 f32
    float* as_  = M20 + (size_t)N_NODES * 20;         // N*4
    float* ad_  = as_ + N_NODES * 4;                  // N*4
    float* pp   = ad_ + N_NODES * 4;                  // 2*N*5 (cls partials)
    int* deg     = (int*)(pp + (size_t)2 * N_NODES * 5);  // N
    int* bsum    = deg + N_NODES;                     // 256
    int* rowptr  = bsum + 256;                        // N+1 (padded to N+4)
    int* csr_src = rowptr + N_NODES + 4;              // E
    unsigned short* Wt1 = (unsigned short*)(csr_src + N_EDGES);  // 256*64
    unsigned short* Wt2 = Wt1 + 256 * 64;                        // 128*256
    unsigned short* Wt3 = Wt2 + 128 * 256;                       // 256*256
    unsigned short* Ab  = Wt3 + 256 * 256;                       // N*256 bf16 (h1)
    unsigned short* Cb  = Ab + (size_t)N_NODES * 256;            // N*128 bf16 (gat h)
    unsigned short* Db  = Cb + (size_t)N_NODES * 128;            // N*128 bf16 (gat out)
    unsigned short* Mb  = Db + (size_t)N_NODES * 128;            // N*128 bf16 (sage2 mean)

    const int MB = (N_NODES + 127) / 128;             // 391 row-blocks

    // ---- weights + deg zero (1 launch) ----
    wt_all_k<<<(114688 + TPB - 1) / TPB, TPB, 0, stream>>>(s1Wl, s1Wr, gW, s2Wl, s2Wr,
                                                           Wt1, Wt2, Wt3, deg);

    // ---- CSR build ----
    hist_k<<<(N_EDGES + TPB - 1) / TPB, TPB, 0, stream>>>(dst, deg);
    scan1_k<<<NCHUNK, 256, 0, stream>>>(deg, rowptr, bsum);
    scan2_k<<<1, 256, 0, stream>>>(bsum);
    scan3_k<<<NCHUNK, 256, 0, stream>>>(rowptr, bsum);
    fill_k<<<(N_EDGES + TPB - 1) / TPB, TPB, 0, stream>>>(src, dst, rowptr, deg, csr_src);

    // ---- SAGE1: Ab = bf16(relu([mean(x)|x] @ Wt1 + b)), K=40 (Kp=64) ----
    gm20_k<<<(N_NODES + 7) / 8, 256, 0, stream>>>(rowptr, csr_src, x, M20);
    gemm_mfma<1><<<dim3(2, MB), 256, 0, stream>>>(M20, 20, x, 20, Wt1, 64, s1b, Ab, 256);

    // ---- GAT: Cb = bf16(Ab @ Wt2), K=256; scores; fused gather -> Db ----
    gemm_mfma_bf<0, 0><<<dim3(1, MB), 256, 0, stream>>>(Ab, 256, nullptr, 0, Wt2, 256,
                                                        nullptr, Cb, 128, nullptr, nullptr);
    att_scores_bf<<<(N_NODES * 4 + TPB - 1) / TPB, TPB, 0, stream>>>(Cb, gas, gad, as_, ad_);
    gat_gather_bf<<<N_NODES / 8, 256, 0, stream>>>(rowptr, csr_src, Cb, as_, ad_, gb, Db);

    // ---- SAGE2 + fused classifier partials: pp[cb][n][5] ----
    gather_mean_bf<<<N_NODES / 8, 256, 0, stream>>>(rowptr, csr_src, Db, Mb);
    gemm_mfma_bf<1, 1><<<dim3(2, MB), 256, 0, stream>>>(Mb, 128, Db, 128, Wt3, 256, s2b,
                                                        nullptr, 256, clsW, pp);

    // ---- combine partials + bias ----
    combine_k<<<(N_NODES * 5 + TPB - 1) / TPB, TPB, 0, stream>>>(pp, clsb, out);
}

// Round 17
// 286.868 us; speedup vs baseline: 1.0431x; 1.0431x over previous
//
#include <hip/hip_runtime.h>
#include <math.h>

#define N_NODES 50000
#define N_EDGES 800000
#define TPB 256
#define NCHUNK ((N_NODES + 255) / 256)   // 196 scan blocks

typedef short s16x8 __attribute__((ext_vector_type(8)));
typedef float f32x4 __attribute__((ext_vector_type(4)));

__device__ __forceinline__ unsigned short f2bf(float f) {
    unsigned u = __float_as_uint(f);
    u += 0x7fffu + ((u >> 16) & 1u);          // round-to-nearest-even
    return (unsigned short)(u >> 16);
}
__device__ __forceinline__ float bf2f(unsigned short h) {
    return __uint_as_float(((unsigned)h) << 16);
}

// ---------------- weight transposes + bf16 cast + deg zero, one launch ----------------
__global__ void wt_all_k(const float* __restrict__ s1Wl, const float* __restrict__ s1Wr,
                         const float* __restrict__ gW, const float* __restrict__ s2Wl,
                         const float* __restrict__ s2Wr, unsigned short* __restrict__ Wt1,
                         unsigned short* __restrict__ Wt2, unsigned short* __restrict__ Wt3,
                         int* __restrict__ deg) {
    int idx = blockIdx.x * TPB + threadIdx.x;
    if (idx < N_NODES) deg[idx] = 0;
    if (idx < 16384) {                       // 256*64
        int n = idx >> 6, k = idx & 63;
        float v = 0.f;
        if (k < 20) v = s1Wl[k * 256 + n];
        else if (k < 40) v = s1Wr[(k - 20) * 256 + n];
        Wt1[idx] = f2bf(v);
    } else if (idx < 49152) {                // + 128*256
        int j = idx - 16384;
        int n = j >> 8, k = j & 255;
        Wt2[j] = f2bf(gW[(size_t)k * 128 + n]);
    } else if (idx < 114688) {               // + 256*256
        int j = idx - 49152;
        int n = j >> 8, k = j & 255;
        float v = (k < 128) ? s2Wl[(size_t)k * 256 + n] : s2Wr[(size_t)(k - 128) * 256 + n];
        Wt3[j] = f2bf(v);
    }
}

// ---------------- bf16 MFMA GEMM, f32 A inputs (SAGE1) ----------------
template<int ACT>
__global__ void gemm_mfma(const float* __restrict__ A1, int K1,
                          const float* __restrict__ A2, int K2,
                          const unsigned short* __restrict__ Wt, int Kp,
                          const float* __restrict__ bias,
                          unsigned short* __restrict__ outb, int NO) {
    constexpr int BM = 128, BK = 32, LDP = 40;
    __shared__ unsigned short sA[BM * LDP];
    __shared__ unsigned short sB[128 * LDP];
    const int K = K1 + K2;
    const int T = Kp / BK;
    const int tid = threadIdx.x;
    const int lane = tid & 63, wid = tid >> 6;
    const int wr = wid >> 1, wc = wid & 1;
    const int row0 = blockIdx.y * BM, col0 = blockIdx.x * 128;
    const int l15 = lane & 15, l4 = lane >> 4;
    f32x4 acc[4][4] = {};

    for (int t = 0; t < T; ++t) {
        __syncthreads();
#pragma unroll
        for (int j = 0; j < 4; ++j) {
            int e = tid + j * 256;
            int r = e >> 3, k4 = e & 7;
            int kg = t * BK + k4 * 4, mg = row0 + r;
            float4 v = {0.f, 0.f, 0.f, 0.f};
            if (mg < N_NODES) {
                if (kg < K1)     v = *(const float4*)&A1[(size_t)mg * K1 + kg];
                else if (kg < K) v = *(const float4*)&A2[(size_t)mg * K2 + (kg - K1)];
            }
            ushort4 b;
            b.x = f2bf(v.x); b.y = f2bf(v.y); b.z = f2bf(v.z); b.w = f2bf(v.w);
            *(ushort4*)&sA[r * LDP + k4 * 4] = b;
        }
#pragma unroll
        for (int j = 0; j < 2; ++j) {
            int e = tid + j * 256;
            int n = e >> 2, k8 = e & 3;
            int4 v = *(const int4*)&Wt[(size_t)(col0 + n) * Kp + t * BK + k8 * 8];
            *(int4*)&sB[n * LDP + k8 * 8] = v;
        }
        __syncthreads();
        s16x8 af[4], bfr[4];
#pragma unroll
        for (int i = 0; i < 4; ++i) {
            af[i]  = *(const s16x8*)&sA[(wr * 64 + i * 16 + l15) * LDP + l4 * 8];
            bfr[i] = *(const s16x8*)&sB[(wc * 64 + i * 16 + l15) * LDP + l4 * 8];
        }
#pragma unroll
        for (int mi = 0; mi < 4; ++mi)
#pragma unroll
            for (int ni = 0; ni < 4; ++ni)
                acc[mi][ni] = __builtin_amdgcn_mfma_f32_16x16x32_bf16(
                    af[mi], bfr[ni], acc[mi][ni], 0, 0, 0);
    }
#pragma unroll
    for (int mi = 0; mi < 4; ++mi) {
#pragma unroll
        for (int ni = 0; ni < 4; ++ni) {
            int col = col0 + wc * 64 + ni * 16 + l15;
            float bb = bias ? bias[col] : 0.f;
#pragma unroll
            for (int r = 0; r < 4; ++r) {
                int row = row0 + wr * 64 + mi * 16 + l4 * 4 + r;
                if (row < N_NODES) {
                    float v = acc[mi][ni][r] + bb;
                    if (ACT) v = fmaxf(v, 0.f);
                    outb[(size_t)row * NO + col] = f2bf(v);
                }
            }
        }
    }
}

// ---------------- bf16 MFMA GEMM, bf16 A inputs (GAT+att-fused / SAGE2+cls-fused) ----
// ATT=1 (GAT): NO==128, col0==0, no bias/act. Writes Cb AND per-(row,head)
//   attention scores as_/ad_ via 16-lane shfl reduction (head = wc*2 + (ni>>1)).
// CLS=1 (SAGE2): skip h3 store; classifier partials into pp[blockIdx.x][n][5].
template<int ACT, int CLS, int ATT>
__global__ void gemm_mfma_bf(const unsigned short* __restrict__ A1, int K1,
                             const unsigned short* __restrict__ A2, int K2,
                             const unsigned short* __restrict__ Wt, int Kp,
                             const float* __restrict__ bias,
                             unsigned short* __restrict__ outb, int NO,
                             const float* __restrict__ clsW, float* __restrict__ pp,
                             const float* __restrict__ att_src,
                             const float* __restrict__ att_dst,
                             float* __restrict__ as_, float* __restrict__ ad_) {
    constexpr int BM = 128, BK = 32, LDP = 40;
    __shared__ unsigned short sA[BM * LDP];    // aliased by sClsW in CLS epilogue
    __shared__ unsigned short sB[128 * LDP];   // aliased by cp in CLS epilogue
    const int T = Kp / BK;
    const int tid = threadIdx.x;
    const int lane = tid & 63, wid = tid >> 6;
    const int wr = wid >> 1, wc = wid & 1;
    const int row0 = blockIdx.y * BM, col0 = blockIdx.x * 128;
    const int l15 = lane & 15, l4 = lane >> 4;
    f32x4 acc[4][4] = {};

    for (int t = 0; t < T; ++t) {
        __syncthreads();
#pragma unroll
        for (int j = 0; j < 2; ++j) {
            int e = tid + j * 256;
            int r = e >> 2, k8 = e & 3;
            int kg = t * BK + k8 * 8, mg = row0 + r;
            int4 v = {0, 0, 0, 0};
            if (mg < N_NODES) {
                if (kg < K1) v = *(const int4*)&A1[(size_t)mg * K1 + kg];
                else         v = *(const int4*)&A2[(size_t)mg * K2 + (kg - K1)];
            }
            *(int4*)&sA[r * LDP + k8 * 8] = v;
        }
#pragma unroll
        for (int j = 0; j < 2; ++j) {
            int e = tid + j * 256;
            int n = e >> 2, k8 = e & 3;
            int4 v = *(const int4*)&Wt[(size_t)(col0 + n) * Kp + t * BK + k8 * 8];
            *(int4*)&sB[n * LDP + k8 * 8] = v;
        }
        __syncthreads();
        s16x8 af[4], bfr[4];
#pragma unroll
        for (int i = 0; i < 4; ++i) {
            af[i]  = *(const s16x8*)&sA[(wr * 64 + i * 16 + l15) * LDP + l4 * 8];
            bfr[i] = *(const s16x8*)&sB[(wc * 64 + i * 16 + l15) * LDP + l4 * 8];
        }
#pragma unroll
        for (int mi = 0; mi < 4; ++mi)
#pragma unroll
            for (int ni = 0; ni < 4; ++ni)
                acc[mi][ni] = __builtin_amdgcn_mfma_f32_16x16x32_bf16(
                    af[mi], bfr[ni], acc[mi][ni], 0, 0, 0);
    }

    if (ATT) {
        // preload att vectors for this thread's 4 columns (idx depends on ni only)
        float atts[4], attd[4];
#pragma unroll
        for (int ni = 0; ni < 4; ++ni) {
            int ai = (wc * 2 + (ni >> 1)) * 32 + (ni & 1) * 16 + l15;
            atts[ni] = att_src[ai];
            attd[ni] = att_dst[ai];
        }
#pragma unroll
        for (int mi = 0; mi < 4; ++mi) {
#pragma unroll
            for (int r = 0; r < 4; ++r) {
                int row = row0 + wr * 64 + mi * 16 + l4 * 4 + r;
                float sa0 = 0.f, sd0 = 0.f, sa1 = 0.f, sd1 = 0.f;
#pragma unroll
                for (int ni = 0; ni < 4; ++ni) {
                    int col = wc * 64 + ni * 16 + l15;
                    unsigned short hb = f2bf(acc[mi][ni][r]);
                    if (row < N_NODES) outb[(size_t)row * 128 + col] = hb;
                    float v = bf2f(hb);
                    if (ni < 2) { sa0 = fmaf(v, atts[ni], sa0); sd0 = fmaf(v, attd[ni], sd0); }
                    else        { sa1 = fmaf(v, atts[ni], sa1); sd1 = fmaf(v, attd[ni], sd1); }
                }
#pragma unroll
                for (int msk = 1; msk < 16; msk <<= 1) {
                    sa0 += __shfl_xor(sa0, msk, 16);
                    sd0 += __shfl_xor(sd0, msk, 16);
                    sa1 += __shfl_xor(sa1, msk, 16);
                    sd1 += __shfl_xor(sd1, msk, 16);
                }
                if (l15 == 0 && row < N_NODES) {
                    as_[row * 4 + wc * 2]     = sa0;
                    ad_[row * 4 + wc * 2]     = sd0;
                    as_[row * 4 + wc * 2 + 1] = sa1;
                    ad_[row * 4 + wc * 2 + 1] = sd1;
                }
            }
        }
    } else if (CLS == 0) {
#pragma unroll
        for (int mi = 0; mi < 4; ++mi) {
#pragma unroll
            for (int ni = 0; ni < 4; ++ni) {
                int col = col0 + wc * 64 + ni * 16 + l15;
                float bb = bias ? bias[col] : 0.f;
#pragma unroll
                for (int r = 0; r < 4; ++r) {
                    int row = row0 + wr * 64 + mi * 16 + l4 * 4 + r;
                    if (row < N_NODES) {
                        float v = acc[mi][ni][r] + bb;
                        if (ACT) v = fmaxf(v, 0.f);
                        outb[(size_t)row * NO + col] = f2bf(v);
                    }
                }
            }
        }
    } else {
        __syncthreads();                      // all LDS reads of last tile done
        float* sClsW = (float*)sA;            // 640 floats
        float* cp    = (float*)sB;            // 2 planes x 128 x 5 floats
        for (int i = tid; i < 640; i += 256)
            sClsW[i] = clsW[(size_t)(col0 + i / 5) * 5 + (i % 5)];
        __syncthreads();
        float bcol[4];
#pragma unroll
        for (int ni = 0; ni < 4; ++ni)
            bcol[ni] = bias[col0 + wc * 64 + ni * 16 + l15];
#pragma unroll
        for (int mi = 0; mi < 4; ++mi) {
#pragma unroll
            for (int r = 0; r < 4; ++r) {
                float p0 = 0.f, p1 = 0.f, p2 = 0.f, p3 = 0.f, p4 = 0.f;
#pragma unroll
                for (int ni = 0; ni < 4; ++ni) {
                    float v = fmaxf(acc[mi][ni][r] + bcol[ni], 0.f);   // relu(h3)
                    const float* w = &sClsW[(wc * 64 + ni * 16 + l15) * 5];
                    p0 = fmaf(v, w[0], p0); p1 = fmaf(v, w[1], p1);
                    p2 = fmaf(v, w[2], p2); p3 = fmaf(v, w[3], p3);
                    p4 = fmaf(v, w[4], p4);
                }
#pragma unroll
                for (int msk = 1; msk < 16; msk <<= 1) {
                    p0 += __shfl_xor(p0, msk, 16);
                    p1 += __shfl_xor(p1, msk, 16);
                    p2 += __shfl_xor(p2, msk, 16);
                    p3 += __shfl_xor(p3, msk, 16);
                    p4 += __shfl_xor(p4, msk, 16);
                }
                if (l15 == 0) {
                    int rr = wr * 64 + mi * 16 + l4 * 4 + r;   // 0..127
                    float* d = &cp[(wc * 128 + rr) * 5];
                    d[0] = p0; d[1] = p1; d[2] = p2; d[3] = p3; d[4] = p4;
                }
            }
        }
        __syncthreads();
        for (int i = tid; i < 640; i += 256) {
            int rr = i / 5, cc = i - rr * 5;
            int row = row0 + rr;
            if (row < N_NODES)
                pp[(size_t)blockIdx.x * ((size_t)N_NODES * 5) + (size_t)row * 5 + cc]
                    = cp[rr * 5 + cc] + cp[(128 + rr) * 5 + cc];
        }
    }
}

// combine classifier partials: out = pp[0] + pp[1] + clsb
__global__ void combine_k(const float* __restrict__ pp, const float* __restrict__ clsb,
                          float* __restrict__ out) {
    int idx = blockIdx.x * TPB + threadIdx.x;
    if (idx >= N_NODES * 5) return;
    int c = idx % 5;
    out[idx] = pp[idx] + pp[(size_t)N_NODES * 5 + idx] + clsb[c];
}

// ---------------- CSR construction ----------------
__global__ void hist_k(const int* __restrict__ dst, int* __restrict__ deg) {
    int e = blockIdx.x * TPB + threadIdx.x;
    if (e < N_EDGES) atomicAdd(&deg[dst[e]], 1);
}

__global__ void scan1_k(const int* __restrict__ deg, int* __restrict__ rowptr,
                        int* __restrict__ bsum) {
    __shared__ int tmp[256];
    int tid = threadIdx.x;
    int idx = blockIdx.x * 256 + tid;
    int v = (idx < N_NODES) ? deg[idx] : 0;
    tmp[tid] = v;
    __syncthreads();
    for (int off = 1; off < 256; off <<= 1) {
        int t = (tid >= off) ? tmp[tid - off] : 0;
        __syncthreads();
        tmp[tid] += t;
        __syncthreads();
    }
    if (idx < N_NODES) rowptr[idx] = tmp[tid] - v;
    if (tid == 255) bsum[blockIdx.x] = tmp[255];
}

__global__ void scan2_k(int* __restrict__ bsum) {
    __shared__ int tmp[256];
    int tid = threadIdx.x;
    int v = (tid < NCHUNK) ? bsum[tid] : 0;
    tmp[tid] = v;
    __syncthreads();
    for (int off = 1; off < 256; off <<= 1) {
        int t = (tid >= off) ? tmp[tid - off] : 0;
        __syncthreads();
        tmp[tid] += t;
        __syncthreads();
    }
    if (tid < NCHUNK) bsum[tid] = tmp[tid] - v;
}

__global__ void scan3_k(int* __restrict__ rowptr, const int* __restrict__ bsum) {
    int idx = blockIdx.x * 256 + threadIdx.x;
    if (idx < N_NODES) rowptr[idx] += bsum[blockIdx.x];
    if (idx == 0) rowptr[N_NODES] = N_EDGES;
}

__global__ void fill_k(const int* __restrict__ src, const int* __restrict__ dst,
                       const int* __restrict__ rowptr, int* __restrict__ deg,
                       int* __restrict__ csr_src) {
    int e = blockIdx.x * TPB + threadIdx.x;
    if (e >= N_EDGES) return;
    int d = dst[e];
    int r = atomicSub(&deg[d], 1) - 1;
    csr_src[rowptr[d] + r] = src[e];
}

// ---------------- gather aggregations ----------------
// SAGE1 mean (F=20, f32): 32-lane group per node, 8 nodes per 256-block
__global__ void gm20_k(const int* __restrict__ rowptr, const int* __restrict__ csr_src,
                       const float* __restrict__ feat, float* __restrict__ out) {
    int tid = threadIdx.x;
    int n = blockIdx.x * 8 + (tid >> 5);
    int c = tid & 31;
    if (n >= N_NODES || c >= 20) return;
    int e0 = rowptr[n], e1 = rowptr[n + 1];
    float acc = 0.f;
    int e = e0;
    for (; e + 1 < e1; e += 2) {
        acc += feat[(size_t)csr_src[e] * 20 + c] + feat[(size_t)csr_src[e + 1] * 20 + c];
    }
    if (e < e1) acc += feat[(size_t)csr_src[e] * 20 + c];
    out[(size_t)n * 20 + c] = acc / fmaxf((float)(e1 - e0), 1.0f);
}

// bf16 mean for F=128: 32 lanes/node, 8 nodes/block, 8-edge unroll
__global__ void gather_mean_bf(const int* __restrict__ rowptr, const int* __restrict__ csr_src,
                               const unsigned short* __restrict__ featb,
                               unsigned short* __restrict__ outb) {
    int tid = threadIdx.x;
    int n = blockIdx.x * 8 + (tid >> 5);
    int c = tid & 31;
    int e0 = rowptr[n], e1 = rowptr[n + 1];
    float4 acc = {0.f, 0.f, 0.f, 0.f};
    int e = e0;
    for (; e + 7 < e1; e += 8) {
        ushort4 u[8];
#pragma unroll
        for (int j = 0; j < 8; ++j)
            u[j] = *(const ushort4*)&featb[(size_t)csr_src[e + j] * 128 + c * 4];
#pragma unroll
        for (int j = 0; j < 8; ++j) {
            acc.x += bf2f(u[j].x); acc.y += bf2f(u[j].y);
            acc.z += bf2f(u[j].z); acc.w += bf2f(u[j].w);
        }
    }
    for (; e < e1; ++e) {
        ushort4 u = *(const ushort4*)&featb[(size_t)csr_src[e] * 128 + c * 4];
        acc.x += bf2f(u.x); acc.y += bf2f(u.y); acc.z += bf2f(u.z); acc.w += bf2f(u.w);
    }
    float inv = 1.0f / fmaxf((float)(e1 - e0), 1.0f);
    ushort4 o;
    o.x = f2bf(acc.x * inv); o.y = f2bf(acc.y * inv);
    o.z = f2bf(acc.z * inv); o.w = f2bf(acc.w * inv);
    *(ushort4*)&outb[(size_t)n * 128 + c * 4] = o;
}

// fused GAT aggregation: bf16 gather, 4-edge-unrolled online softmax, ELU, bf16 out
// (round-15 version: proven 48us; R16's shfl-dedup regressed to 50us)
__global__ void gat_gather_bf(const int* __restrict__ rowptr, const int* __restrict__ csr_src,
                              const unsigned short* __restrict__ hb,
                              const float* __restrict__ as_, const float* __restrict__ ad_,
                              const float* __restrict__ gb,
                              unsigned short* __restrict__ outb) {
    int tid = threadIdx.x;
    int n = blockIdx.x * 8 + (tid >> 5);
    int c = tid & 31;              // float4 index within row; head = c>>3
    int hd = c >> 3;
    int e0 = rowptr[n], e1 = rowptr[n + 1];
    float ad = ad_[n * 4 + hd];
    float m = -INFINITY, s = 0.f;
    float4 acc = {0.f, 0.f, 0.f, 0.f};
    int e = e0;
    for (; e + 3 < e1; e += 4) {
        int s0 = csr_src[e], s1 = csr_src[e + 1], s2 = csr_src[e + 2], s3 = csr_src[e + 3];
        float a0 = as_[s0 * 4 + hd] + ad;
        float a1 = as_[s1 * 4 + hd] + ad;
        float a2 = as_[s2 * 4 + hd] + ad;
        float a3 = as_[s3 * 4 + hd] + ad;
        a0 = a0 >= 0.f ? a0 : 0.2f * a0;
        a1 = a1 >= 0.f ? a1 : 0.2f * a1;
        a2 = a2 >= 0.f ? a2 : 0.2f * a2;
        a3 = a3 >= 0.f ? a3 : 0.2f * a3;
        float pm = fmaxf(fmaxf(a0, a1), fmaxf(a2, a3));
        if (pm > m) {                              // one rescale per 4 edges
            float sc = __expf(m - pm);
            s *= sc; acc.x *= sc; acc.y *= sc; acc.z *= sc; acc.w *= sc;
            m = pm;
        }
        float ex0 = __expf(a0 - m), ex1 = __expf(a1 - m);
        float ex2 = __expf(a2 - m), ex3 = __expf(a3 - m);
        s += (ex0 + ex1) + (ex2 + ex3);
        ushort4 u0 = *(const ushort4*)&hb[(size_t)s0 * 128 + c * 4];
        ushort4 u1 = *(const ushort4*)&hb[(size_t)s1 * 128 + c * 4];
        ushort4 u2 = *(const ushort4*)&hb[(size_t)s2 * 128 + c * 4];
        ushort4 u3 = *(const ushort4*)&hb[(size_t)s3 * 128 + c * 4];
        acc.x = fmaf(bf2f(u0.x), ex0, acc.x); acc.y = fmaf(bf2f(u0.y), ex0, acc.y);
        acc.z = fmaf(bf2f(u0.z), ex0, acc.z); acc.w = fmaf(bf2f(u0.w), ex0, acc.w);
        acc.x = fmaf(bf2f(u1.x), ex1, acc.x); acc.y = fmaf(bf2f(u1.y), ex1, acc.y);
        acc.z = fmaf(bf2f(u1.z), ex1, acc.z); acc.w = fmaf(bf2f(u1.w), ex1, acc.w);
        acc.x = fmaf(bf2f(u2.x), ex2, acc.x); acc.y = fmaf(bf2f(u2.y), ex2, acc.y);
        acc.z = fmaf(bf2f(u2.z), ex2, acc.z); acc.w = fmaf(bf2f(u2.w), ex2, acc.w);
        acc.x = fmaf(bf2f(u3.x), ex3, acc.x); acc.y = fmaf(bf2f(u3.y), ex3, acc.y);
        acc.z = fmaf(bf2f(u3.z), ex3, acc.z); acc.w = fmaf(bf2f(u3.w), ex3, acc.w);
    }
    for (; e < e1; ++e) {
        int s0 = csr_src[e];
        float a = as_[s0 * 4 + hd] + ad;
        a = a >= 0.f ? a : 0.2f * a;
        if (a > m) {
            float sc = __expf(m - a);
            s *= sc; acc.x *= sc; acc.y *= sc; acc.z *= sc; acc.w *= sc;
            m = a;
        }
        float ex = __expf(a - m);
        s += ex;
        ushort4 u = *(const ushort4*)&hb[(size_t)s0 * 128 + c * 4];
        acc.x = fmaf(bf2f(u.x), ex, acc.x); acc.y = fmaf(bf2f(u.y), ex, acc.y);
        acc.z = fmaf(bf2f(u.z), ex, acc.z); acc.w = fmaf(bf2f(u.w), ex, acc.w);
    }
    float inv = 1.0f / (s + 1e-16f);
    float rx = acc.x * inv + gb[c * 4 + 0];
    float ry = acc.y * inv + gb[c * 4 + 1];
    float rz = acc.z * inv + gb[c * 4 + 2];
    float rw = acc.w * inv + gb[c * 4 + 3];
    rx = rx > 0.f ? rx : expm1f(rx);
    ry = ry > 0.f ? ry : expm1f(ry);
    rz = rz > 0.f ? rz : expm1f(rz);
    rw = rw > 0.f ? rw : expm1f(rw);
    ushort4 o;
    o.x = f2bf(rx); o.y = f2bf(ry); o.z = f2bf(rz); o.w = f2bf(rw);
    *(ushort4*)&outb[(size_t)n * 128 + c * 4] = o;
}

extern "C" void kernel_launch(void* const* d_in, const int* in_sizes, int n_in,
                              void* d_out, int out_size, void* d_ws, size_t ws_size,
                              hipStream_t stream) {
    const float* x    = (const float*)d_in[0];
    const int*   ei   = (const int*)d_in[1];
    const float* s1Wl = (const float*)d_in[2];
    const float* s1Wr = (const float*)d_in[3];
    const float* s1b  = (const float*)d_in[4];
    const float* gW   = (const float*)d_in[5];
    const float* gas  = (const float*)d_in[6];
    const float* gad  = (const float*)d_in[7];
    const float* gb   = (const float*)d_in[8];
    const float* s2Wl = (const float*)d_in[9];
    const float* s2Wr = (const float*)d_in[10];
    const float* s2b  = (const float*)d_in[11];
    const float* clsW = (const float*)d_in[12];
    const float* clsb = (const float*)d_in[13];
    float* out = (float*)d_out;
    const int* src = ei;            // edge_index[0]
    const int* dst = ei + N_EDGES;  // edge_index[1]

    // ---- workspace layout (16B-aligned segments) ----
    float* ws  = (float*)d_ws;
    float* M20  = ws;                                 // N*20 f32
    float* as_  = M20 + (size_t)N_NODES * 20;         // N*4
    float* ad_  = as_ + N_NODES * 4;                  // N*4
    float* pp   = ad_ + N_NODES * 4;                  // 2*N*5 (cls partials)
    int* deg     = (int*)(pp + (size_t)2 * N_NODES * 5);  // N
    int* bsum    = deg + N_NODES;                     // 256
    int* rowptr  = bsum + 256;                        // N+1 (padded to N+4)
    int* csr_src = rowptr + N_NODES + 4;              // E
    unsigned short* Wt1 = (unsigned short*)(csr_src + N_EDGES);  // 256*64
    unsigned short* Wt2 = Wt1 + 256 * 64;                        // 128*256
    unsigned short* Wt3 = Wt2 + 128 * 256;                       // 256*256
    unsigned short* Ab  = Wt3 + 256 * 256;                       // N*256 bf16 (h1)
    unsigned short* Cb  = Ab + (size_t)N_NODES * 256;            // N*128 bf16 (gat h)
    unsigned short* Db  = Cb + (size_t)N_NODES * 128;            // N*128 bf16 (gat out)
    unsigned short* Mb  = Db + (size_t)N_NODES * 128;            // N*128 bf16 (sage2 mean)

    const int MB = (N_NODES + 127) / 128;             // 391 row-blocks

    // ---- weights + deg zero (1 launch) ----
    wt_all_k<<<(114688 + TPB - 1) / TPB, TPB, 0, stream>>>(s1Wl, s1Wr, gW, s2Wl, s2Wr,
                                                           Wt1, Wt2, Wt3, deg);

    // ---- CSR build ----
    hist_k<<<(N_EDGES + TPB - 1) / TPB, TPB, 0, stream>>>(dst, deg);
    scan1_k<<<NCHUNK, 256, 0, stream>>>(deg, rowptr, bsum);
    scan2_k<<<1, 256, 0, stream>>>(bsum);
    scan3_k<<<NCHUNK, 256, 0, stream>>>(rowptr, bsum);
    fill_k<<<(N_EDGES + TPB - 1) / TPB, TPB, 0, stream>>>(src, dst, rowptr, deg, csr_src);

    // ---- SAGE1: Ab = bf16(relu([mean(x)|x] @ Wt1 + b)), K=40 (Kp=64) ----
    gm20_k<<<(N_NODES + 7) / 8, 256, 0, stream>>>(rowptr, csr_src, x, M20);
    gemm_mfma<1><<<dim3(2, MB), 256, 0, stream>>>(M20, 20, x, 20, Wt1, 64, s1b, Ab, 256);

    // ---- GAT: Cb = bf16(Ab @ Wt2) + fused att scores; fused gather -> Db ----
    gemm_mfma_bf<0, 0, 1><<<dim3(1, MB), 256, 0, stream>>>(
        Ab, 256, nullptr, 0, Wt2, 256, nullptr, Cb, 128,
        nullptr, nullptr, gas, gad, as_, ad_);
    gat_gather_bf<<<N_NODES / 8, 256, 0, stream>>>(rowptr, csr_src, Cb, as_, ad_, gb, Db);

    // ---- SAGE2 + fused classifier partials: pp[cb][n][5] ----
    gather_mean_bf<<<N_NODES / 8, 256, 0, stream>>>(rowptr, csr_src, Db, Mb);
    gemm_mfma_bf<1, 1, 0><<<dim3(2, MB), 256, 0, stream>>>(
        Mb, 128, Db, 128, Wt3, 256, s2b, nullptr, 256, clsW, pp,
        nullptr, nullptr, nullptr, nullptr);

    // ---- combine partials + bias ----
    combine_k<<<(N_NODES * 5 + TPB - 1) / TPB, TPB, 0, stream>>>(pp, clsb, out);
}

// Round 18
// 285.935 us; speedup vs baseline: 1.0466x; 1.0033x over previous
//
#include <hip/hip_runtime.h>
#include <math.h>

#define N_NODES 50000
#define N_EDGES 800000
#define TPB 256
#define NCHUNK ((N_NODES + 255) / 256)   // 196 scan blocks

typedef short s16x8 __attribute__((ext_vector_type(8)));
typedef float f32x4 __attribute__((ext_vector_type(4)));

__device__ __forceinline__ unsigned short f2bf(float f) {
    unsigned u = __float_as_uint(f);
    u += 0x7fffu + ((u >> 16) & 1u);          // round-to-nearest-even
    return (unsigned short)(u >> 16);
}
__device__ __forceinline__ float bf2f(unsigned short h) {
    return __uint_as_float(((unsigned)h) << 16);
}

// ---------------- weight transposes + bf16 cast + deg zero, one launch ----------------
__global__ void wt_all_k(const float* __restrict__ s1Wl, const float* __restrict__ s1Wr,
                         const float* __restrict__ gW, const float* __restrict__ s2Wl,
                         const float* __restrict__ s2Wr, unsigned short* __restrict__ Wt1,
                         unsigned short* __restrict__ Wt2, unsigned short* __restrict__ Wt3,
                         int* __restrict__ deg) {
    int idx = blockIdx.x * TPB + threadIdx.x;
    if (idx < N_NODES) deg[idx] = 0;
    if (idx < 16384) {                       // 256*64
        int n = idx >> 6, k = idx & 63;
        float v = 0.f;
        if (k < 20) v = s1Wl[k * 256 + n];
        else if (k < 40) v = s1Wr[(k - 20) * 256 + n];
        Wt1[idx] = f2bf(v);
    } else if (idx < 49152) {                // + 128*256
        int j = idx - 16384;
        int n = j >> 8, k = j & 255;
        Wt2[j] = f2bf(gW[(size_t)k * 128 + n]);
    } else if (idx < 114688) {               // + 256*256
        int j = idx - 49152;
        int n = j >> 8, k = j & 255;
        float v = (k < 128) ? s2Wl[(size_t)k * 256 + n] : s2Wr[(size_t)(k - 128) * 256 + n];
        Wt3[j] = f2bf(v);
    }
}

// ---------------- bf16 MFMA GEMM, f32 A inputs (SAGE1) ----------------
template<int ACT>
__global__ void gemm_mfma(const float* __restrict__ A1, int K1,
                          const float* __restrict__ A2, int K2,
                          const unsigned short* __restrict__ Wt, int Kp,
                          const float* __restrict__ bias,
                          unsigned short* __restrict__ outb, int NO) {
    constexpr int BM = 128, BK = 32, LDP = 40;
    __shared__ unsigned short sA[BM * LDP];
    __shared__ unsigned short sB[128 * LDP];
    const int K = K1 + K2;
    const int T = Kp / BK;
    const int tid = threadIdx.x;
    const int lane = tid & 63, wid = tid >> 6;
    const int wr = wid >> 1, wc = wid & 1;
    const int row0 = blockIdx.y * BM, col0 = blockIdx.x * 128;
    const int l15 = lane & 15, l4 = lane >> 4;
    f32x4 acc[4][4] = {};

    for (int t = 0; t < T; ++t) {
        __syncthreads();
#pragma unroll
        for (int j = 0; j < 4; ++j) {
            int e = tid + j * 256;
            int r = e >> 3, k4 = e & 7;
            int kg = t * BK + k4 * 4, mg = row0 + r;
            float4 v = {0.f, 0.f, 0.f, 0.f};
            if (mg < N_NODES) {
                if (kg < K1)     v = *(const float4*)&A1[(size_t)mg * K1 + kg];
                else if (kg < K) v = *(const float4*)&A2[(size_t)mg * K2 + (kg - K1)];
            }
            ushort4 b;
            b.x = f2bf(v.x); b.y = f2bf(v.y); b.z = f2bf(v.z); b.w = f2bf(v.w);
            *(ushort4*)&sA[r * LDP + k4 * 4] = b;
        }
#pragma unroll
        for (int j = 0; j < 2; ++j) {
            int e = tid + j * 256;
            int n = e >> 2, k8 = e & 3;
            int4 v = *(const int4*)&Wt[(size_t)(col0 + n) * Kp + t * BK + k8 * 8];
            *(int4*)&sB[n * LDP + k8 * 8] = v;
        }
        __syncthreads();
        s16x8 af[4], bfr[4];
#pragma unroll
        for (int i = 0; i < 4; ++i) {
            af[i]  = *(const s16x8*)&sA[(wr * 64 + i * 16 + l15) * LDP + l4 * 8];
            bfr[i] = *(const s16x8*)&sB[(wc * 64 + i * 16 + l15) * LDP + l4 * 8];
        }
#pragma unroll
        for (int mi = 0; mi < 4; ++mi)
#pragma unroll
            for (int ni = 0; ni < 4; ++ni)
                acc[mi][ni] = __builtin_amdgcn_mfma_f32_16x16x32_bf16(
                    af[mi], bfr[ni], acc[mi][ni], 0, 0, 0);
    }
#pragma unroll
    for (int mi = 0; mi < 4; ++mi) {
#pragma unroll
        for (int ni = 0; ni < 4; ++ni) {
            int col = col0 + wc * 64 + ni * 16 + l15;
            float bb = bias ? bias[col] : 0.f;
#pragma unroll
            for (int r = 0; r < 4; ++r) {
                int row = row0 + wr * 64 + mi * 16 + l4 * 4 + r;
                if (row < N_NODES) {
                    float v = acc[mi][ni][r] + bb;
                    if (ACT) v = fmaxf(v, 0.f);
                    outb[(size_t)row * NO + col] = f2bf(v);
                }
            }
        }
    }
}

// ---------------- bf16 MFMA GEMM, bf16 A inputs (GAT+att-fused / SAGE2+cls-fused) ----
template<int ACT, int CLS, int ATT>
__global__ void gemm_mfma_bf(const unsigned short* __restrict__ A1, int K1,
                             const unsigned short* __restrict__ A2, int K2,
                             const unsigned short* __restrict__ Wt, int Kp,
                             const float* __restrict__ bias,
                             unsigned short* __restrict__ outb, int NO,
                             const float* __restrict__ clsW, float* __restrict__ pp,
                             const float* __restrict__ att_src,
                             const float* __restrict__ att_dst,
                             float* __restrict__ as_, float* __restrict__ ad_) {
    constexpr int BM = 128, BK = 32, LDP = 40;
    __shared__ unsigned short sA[BM * LDP];    // aliased by sClsW in CLS epilogue
    __shared__ unsigned short sB[128 * LDP];   // aliased by cp in CLS epilogue
    const int T = Kp / BK;
    const int tid = threadIdx.x;
    const int lane = tid & 63, wid = tid >> 6;
    const int wr = wid >> 1, wc = wid & 1;
    const int row0 = blockIdx.y * BM, col0 = blockIdx.x * 128;
    const int l15 = lane & 15, l4 = lane >> 4;
    f32x4 acc[4][4] = {};

    for (int t = 0; t < T; ++t) {
        __syncthreads();
#pragma unroll
        for (int j = 0; j < 2; ++j) {
            int e = tid + j * 256;
            int r = e >> 2, k8 = e & 3;
            int kg = t * BK + k8 * 8, mg = row0 + r;
            int4 v = {0, 0, 0, 0};
            if (mg < N_NODES) {
                if (kg < K1) v = *(const int4*)&A1[(size_t)mg * K1 + kg];
                else         v = *(const int4*)&A2[(size_t)mg * K2 + (kg - K1)];
            }
            *(int4*)&sA[r * LDP + k8 * 8] = v;
        }
#pragma unroll
        for (int j = 0; j < 2; ++j) {
            int e = tid + j * 256;
            int n = e >> 2, k8 = e & 3;
            int4 v = *(const int4*)&Wt[(size_t)(col0 + n) * Kp + t * BK + k8 * 8];
            *(int4*)&sB[n * LDP + k8 * 8] = v;
        }
        __syncthreads();
        s16x8 af[4], bfr[4];
#pragma unroll
        for (int i = 0; i < 4; ++i) {
            af[i]  = *(const s16x8*)&sA[(wr * 64 + i * 16 + l15) * LDP + l4 * 8];
            bfr[i] = *(const s16x8*)&sB[(wc * 64 + i * 16 + l15) * LDP + l4 * 8];
        }
#pragma unroll
        for (int mi = 0; mi < 4; ++mi)
#pragma unroll
            for (int ni = 0; ni < 4; ++ni)
                acc[mi][ni] = __builtin_amdgcn_mfma_f32_16x16x32_bf16(
                    af[mi], bfr[ni], acc[mi][ni], 0, 0, 0);
    }

    if (ATT) {
        float atts[4], attd[4];
#pragma unroll
        for (int ni = 0; ni < 4; ++ni) {
            int ai = (wc * 2 + (ni >> 1)) * 32 + (ni & 1) * 16 + l15;
            atts[ni] = att_src[ai];
            attd[ni] = att_dst[ai];
        }
#pragma unroll
        for (int mi = 0; mi < 4; ++mi) {
#pragma unroll
            for (int r = 0; r < 4; ++r) {
                int row = row0 + wr * 64 + mi * 16 + l4 * 4 + r;
                float sa0 = 0.f, sd0 = 0.f, sa1 = 0.f, sd1 = 0.f;
#pragma unroll
                for (int ni = 0; ni < 4; ++ni) {
                    int col = wc * 64 + ni * 16 + l15;
                    unsigned short hb = f2bf(acc[mi][ni][r]);
                    if (row < N_NODES) outb[(size_t)row * 128 + col] = hb;
                    float v = bf2f(hb);
                    if (ni < 2) { sa0 = fmaf(v, atts[ni], sa0); sd0 = fmaf(v, attd[ni], sd0); }
                    else        { sa1 = fmaf(v, atts[ni], sa1); sd1 = fmaf(v, attd[ni], sd1); }
                }
#pragma unroll
                for (int msk = 1; msk < 16; msk <<= 1) {
                    sa0 += __shfl_xor(sa0, msk, 16);
                    sd0 += __shfl_xor(sd0, msk, 16);
                    sa1 += __shfl_xor(sa1, msk, 16);
                    sd1 += __shfl_xor(sd1, msk, 16);
                }
                if (l15 == 0 && row < N_NODES) {
                    as_[row * 4 + wc * 2]     = sa0;
                    ad_[row * 4 + wc * 2]     = sd0;
                    as_[row * 4 + wc * 2 + 1] = sa1;
                    ad_[row * 4 + wc * 2 + 1] = sd1;
                }
            }
        }
    } else if (CLS == 0) {
#pragma unroll
        for (int mi = 0; mi < 4; ++mi) {
#pragma unroll
            for (int ni = 0; ni < 4; ++ni) {
                int col = col0 + wc * 64 + ni * 16 + l15;
                float bb = bias ? bias[col] : 0.f;
#pragma unroll
                for (int r = 0; r < 4; ++r) {
                    int row = row0 + wr * 64 + mi * 16 + l4 * 4 + r;
                    if (row < N_NODES) {
                        float v = acc[mi][ni][r] + bb;
                        if (ACT) v = fmaxf(v, 0.f);
                        outb[(size_t)row * NO + col] = f2bf(v);
                    }
                }
            }
        }
    } else {
        __syncthreads();
        float* sClsW = (float*)sA;            // 640 floats
        float* cp    = (float*)sB;            // 2 planes x 128 x 5 floats
        for (int i = tid; i < 640; i += 256)
            sClsW[i] = clsW[(size_t)(col0 + i / 5) * 5 + (i % 5)];
        __syncthreads();
        float bcol[4];
#pragma unroll
        for (int ni = 0; ni < 4; ++ni)
            bcol[ni] = bias[col0 + wc * 64 + ni * 16 + l15];
#pragma unroll
        for (int mi = 0; mi < 4; ++mi) {
#pragma unroll
            for (int r = 0; r < 4; ++r) {
                float p0 = 0.f, p1 = 0.f, p2 = 0.f, p3 = 0.f, p4 = 0.f;
#pragma unroll
                for (int ni = 0; ni < 4; ++ni) {
                    float v = fmaxf(acc[mi][ni][r] + bcol[ni], 0.f);   // relu(h3)
                    const float* w = &sClsW[(wc * 64 + ni * 16 + l15) * 5];
                    p0 = fmaf(v, w[0], p0); p1 = fmaf(v, w[1], p1);
                    p2 = fmaf(v, w[2], p2); p3 = fmaf(v, w[3], p3);
                    p4 = fmaf(v, w[4], p4);
                }
#pragma unroll
                for (int msk = 1; msk < 16; msk <<= 1) {
                    p0 += __shfl_xor(p0, msk, 16);
                    p1 += __shfl_xor(p1, msk, 16);
                    p2 += __shfl_xor(p2, msk, 16);
                    p3 += __shfl_xor(p3, msk, 16);
                    p4 += __shfl_xor(p4, msk, 16);
                }
                if (l15 == 0) {
                    int rr = wr * 64 + mi * 16 + l4 * 4 + r;   // 0..127
                    float* d = &cp[(wc * 128 + rr) * 5];
                    d[0] = p0; d[1] = p1; d[2] = p2; d[3] = p3; d[4] = p4;
                }
            }
        }
        __syncthreads();
        for (int i = tid; i < 640; i += 256) {
            int rr = i / 5, cc = i - rr * 5;
            int row = row0 + rr;
            if (row < N_NODES)
                pp[(size_t)blockIdx.x * ((size_t)N_NODES * 5) + (size_t)row * 5 + cc]
                    = cp[rr * 5 + cc] + cp[(128 + rr) * 5 + cc];
        }
    }
}

// combine classifier partials: out = pp[0] + pp[1] + clsb
__global__ void combine_k(const float* __restrict__ pp, const float* __restrict__ clsb,
                          float* __restrict__ out) {
    int idx = blockIdx.x * TPB + threadIdx.x;
    if (idx >= N_NODES * 5) return;
    int c = idx % 5;
    out[idx] = pp[idx] + pp[(size_t)N_NODES * 5 + idx] + clsb[c];
}

// ---------------- CSR construction ----------------
__global__ void hist_k(const int* __restrict__ dst, int* __restrict__ deg) {
    int e = blockIdx.x * TPB + threadIdx.x;
    if (e < N_EDGES) atomicAdd(&deg[dst[e]], 1);
}

__global__ void scan1_k(const int* __restrict__ deg, int* __restrict__ rowptr,
                        int* __restrict__ bsum) {
    __shared__ int tmp[256];
    int tid = threadIdx.x;
    int idx = blockIdx.x * 256 + tid;
    int v = (idx < N_NODES) ? deg[idx] : 0;
    tmp[tid] = v;
    __syncthreads();
    for (int off = 1; off < 256; off <<= 1) {
        int t = (tid >= off) ? tmp[tid - off] : 0;
        __syncthreads();
        tmp[tid] += t;
        __syncthreads();
    }
    if (idx < N_NODES) rowptr[idx] = tmp[tid] - v;
    if (tid == 255) bsum[blockIdx.x] = tmp[255];
}

__global__ void scan2_k(int* __restrict__ bsum) {
    __shared__ int tmp[256];
    int tid = threadIdx.x;
    int v = (tid < NCHUNK) ? bsum[tid] : 0;
    tmp[tid] = v;
    __syncthreads();
    for (int off = 1; off < 256; off <<= 1) {
        int t = (tid >= off) ? tmp[tid - off] : 0;
        __syncthreads();
        tmp[tid] += t;
        __syncthreads();
    }
    if (tid < NCHUNK) bsum[tid] = tmp[tid] - v;
}

__global__ void scan3_k(int* __restrict__ rowptr, const int* __restrict__ bsum) {
    int idx = blockIdx.x * 256 + threadIdx.x;
    if (idx < N_NODES) rowptr[idx] += bsum[blockIdx.x];
    if (idx == 0) rowptr[N_NODES] = N_EDGES;
}

__global__ void fill_k(const int* __restrict__ src, const int* __restrict__ dst,
                       const int* __restrict__ rowptr, int* __restrict__ deg,
                       int* __restrict__ csr_src) {
    int e = blockIdx.x * TPB + threadIdx.x;
    if (e >= N_EDGES) return;
    int d = dst[e];
    int r = atomicSub(&deg[d], 1) - 1;
    csr_src[rowptr[d] + r] = src[e];
}

// ---------------- gather aggregations ----------------
// SAGE1 mean (F=20, f32): 32-lane group per node, 8 nodes per 256-block
__global__ void gm20_k(const int* __restrict__ rowptr, const int* __restrict__ csr_src,
                       const float* __restrict__ feat, float* __restrict__ out) {
    int tid = threadIdx.x;
    int n = blockIdx.x * 8 + (tid >> 5);
    int c = tid & 31;
    if (n >= N_NODES || c >= 20) return;
    int e0 = rowptr[n], e1 = rowptr[n + 1];
    float acc = 0.f;
    int e = e0;
    for (; e + 1 < e1; e += 2) {
        acc += feat[(size_t)csr_src[e] * 20 + c] + feat[(size_t)csr_src[e + 1] * 20 + c];
    }
    if (e < e1) acc += feat[(size_t)csr_src[e] * 20 + c];
    out[(size_t)n * 20 + c] = acc / fmaxf((float)(e1 - e0), 1.0f);
}

// bf16 mean for F=128: 32 lanes/node, 8 nodes/block, 8-edge unroll
__global__ void gather_mean_bf(const int* __restrict__ rowptr, const int* __restrict__ csr_src,
                               const unsigned short* __restrict__ featb,
                               unsigned short* __restrict__ outb) {
    int tid = threadIdx.x;
    int n = blockIdx.x * 8 + (tid >> 5);
    int c = tid & 31;
    int e0 = rowptr[n], e1 = rowptr[n + 1];
    float4 acc = {0.f, 0.f, 0.f, 0.f};
    int e = e0;
    for (; e + 7 < e1; e += 8) {
        ushort4 u[8];
#pragma unroll
        for (int j = 0; j < 8; ++j)
            u[j] = *(const ushort4*)&featb[(size_t)csr_src[e + j] * 128 + c * 4];
#pragma unroll
        for (int j = 0; j < 8; ++j) {
            acc.x += bf2f(u[j].x); acc.y += bf2f(u[j].y);
            acc.z += bf2f(u[j].z); acc.w += bf2f(u[j].w);
        }
    }
    for (; e < e1; ++e) {
        ushort4 u = *(const ushort4*)&featb[(size_t)csr_src[e] * 128 + c * 4];
        acc.x += bf2f(u.x); acc.y += bf2f(u.y); acc.z += bf2f(u.z); acc.w += bf2f(u.w);
    }
    float inv = 1.0f / fmaxf((float)(e1 - e0), 1.0f);
    ushort4 o;
    o.x = f2bf(acc.x * inv); o.y = f2bf(acc.y * inv);
    o.z = f2bf(acc.z * inv); o.w = f2bf(acc.w * inv);
    *(ushort4*)&outb[(size_t)n * 128 + c * 4] = o;
}

// fused GAT aggregation: bf16 gather, 8-edge-unrolled online softmax (per-lane,
// no shfl — R16's dedup regressed), ELU, bf16 out. 8 rows in flight per iter.
__global__ void gat_gather_bf(const int* __restrict__ rowptr, const int* __restrict__ csr_src,
                              const unsigned short* __restrict__ hb,
                              const float* __restrict__ as_, const float* __restrict__ ad_,
                              const float* __restrict__ gb,
                              unsigned short* __restrict__ outb) {
    int tid = threadIdx.x;
    int n = blockIdx.x * 8 + (tid >> 5);
    int c = tid & 31;              // float4 index within row; head = c>>3
    int hd = c >> 3;
    int e0 = rowptr[n], e1 = rowptr[n + 1];
    float ad = ad_[n * 4 + hd];
    float m = -INFINITY, s = 0.f;
    float4 acc = {0.f, 0.f, 0.f, 0.f};
    int e = e0;
    for (; e + 7 < e1; e += 8) {
        int sj[8];
#pragma unroll
        for (int j = 0; j < 8; ++j) sj[j] = csr_src[e + j];
        float a[8];
#pragma unroll
        for (int j = 0; j < 8; ++j) {
            float aa = as_[sj[j] * 4 + hd] + ad;
            a[j] = aa >= 0.f ? aa : 0.2f * aa;     // leaky_relu 0.2
        }
        float pm = fmaxf(fmaxf(fmaxf(a[0], a[1]), fmaxf(a[2], a[3])),
                         fmaxf(fmaxf(a[4], a[5]), fmaxf(a[6], a[7])));
        if (pm > m) {                              // one rescale per 8 edges
            float sc = __expf(m - pm);
            s *= sc; acc.x *= sc; acc.y *= sc; acc.z *= sc; acc.w *= sc;
            m = pm;
        }
        float ex[8];
#pragma unroll
        for (int j = 0; j < 8; ++j) ex[j] = __expf(a[j] - m);
        s += ((ex[0] + ex[1]) + (ex[2] + ex[3])) + ((ex[4] + ex[5]) + (ex[6] + ex[7]));
        ushort4 u[8];
#pragma unroll
        for (int j = 0; j < 8; ++j)
            u[j] = *(const ushort4*)&hb[(size_t)sj[j] * 128 + c * 4];
#pragma unroll
        for (int j = 0; j < 8; ++j) {
            acc.x = fmaf(bf2f(u[j].x), ex[j], acc.x);
            acc.y = fmaf(bf2f(u[j].y), ex[j], acc.y);
            acc.z = fmaf(bf2f(u[j].z), ex[j], acc.z);
            acc.w = fmaf(bf2f(u[j].w), ex[j], acc.w);
        }
    }
    for (; e < e1; ++e) {
        int s0 = csr_src[e];
        float aa = as_[s0 * 4 + hd] + ad;
        aa = aa >= 0.f ? aa : 0.2f * aa;
        if (aa > m) {
            float sc = __expf(m - aa);
            s *= sc; acc.x *= sc; acc.y *= sc; acc.z *= sc; acc.w *= sc;
            m = aa;
        }
        float ex = __expf(aa - m);
        s += ex;
        ushort4 u = *(const ushort4*)&hb[(size_t)s0 * 128 + c * 4];
        acc.x = fmaf(bf2f(u.x), ex, acc.x); acc.y = fmaf(bf2f(u.y), ex, acc.y);
        acc.z = fmaf(bf2f(u.z), ex, acc.z); acc.w = fmaf(bf2f(u.w), ex, acc.w);
    }
    float inv = 1.0f / (s + 1e-16f);
    float rx = acc.x * inv + gb[c * 4 + 0];
    float ry = acc.y * inv + gb[c * 4 + 1];
    float rz = acc.z * inv + gb[c * 4 + 2];
    float rw = acc.w * inv + gb[c * 4 + 3];
    rx = rx > 0.f ? rx : expm1f(rx);
    ry = ry > 0.f ? ry : expm1f(ry);
    rz = rz > 0.f ? rz : expm1f(rz);
    rw = rw > 0.f ? rw : expm1f(rw);
    ushort4 o;
    o.x = f2bf(rx); o.y = f2bf(ry); o.z = f2bf(rz); o.w = f2bf(rw);
    *(ushort4*)&outb[(size_t)n * 128 + c * 4] = o;
}

extern "C" void kernel_launch(void* const* d_in, const int* in_sizes, int n_in,
                              void* d_out, int out_size, void* d_ws, size_t ws_size,
                              hipStream_t stream) {
    const float* x    = (const float*)d_in[0];
    const int*   ei   = (const int*)d_in[1];
    const float* s1Wl = (const float*)d_in[2];
    const float* s1Wr = (const float*)d_in[3];
    const float* s1b  = (const float*)d_in[4];
    const float* gW   = (const float*)d_in[5];
    const float* gas  = (const float*)d_in[6];
    const float* gad  = (const float*)d_in[7];
    const float* gb   = (const float*)d_in[8];
    const float* s2Wl = (const float*)d_in[9];
    const float* s2Wr = (const float*)d_in[10];
    const float* s2b  = (const float*)d_in[11];
    const float* clsW = (const float*)d_in[12];
    const float* clsb = (const float*)d_in[13];
    float* out = (float*)d_out;
    const int* src = ei;            // edge_index[0]
    const int* dst = ei + N_EDGES;  // edge_index[1]

    // ---- workspace layout (16B-aligned segments) ----
    float* ws  = (float*)d_ws;
    float* M20  = ws;                                 // N*20 f32
    float* as_  = M20 + (size_t)N_NODES * 20;         // N*4
    float* ad_  = as_ + N_NODES * 4;                  // N*4
    float* pp   = ad_ + N_NODES * 4;                  // 2*N*5 (cls partials)
    int* deg     = (int*)(pp + (size_t)2 * N_NODES * 5);  // N
    int* bsum    = deg + N_NODES;                     // 256
    int* rowptr  = bsum + 256;                        // N+1 (padded to N+4)
    int* csr_src = rowptr + N_NODES + 4;              // E
    unsigned short* Wt1 = (unsigned short*)(csr_src + N_EDGES);  // 256*64
    unsigned short* Wt2 = Wt1 + 256 * 64;                        // 128*256
    unsigned short* Wt3 = Wt2 + 128 * 256;                       // 256*256
    unsigned short* Ab  = Wt3 + 256 * 256;                       // N*256 bf16 (h1)
    unsigned short* Cb  = Ab + (size_t)N_NODES * 256;            // N*128 bf16 (gat h)
    unsigned short* Db  = Cb + (size_t)N_NODES * 128;            // N*128 bf16 (gat out)
    unsigned short* Mb  = Db + (size_t)N_NODES * 128;            // N*128 bf16 (sage2 mean)

    const int MB = (N_NODES + 127) / 128;             // 391 row-blocks

    // ---- weights + deg zero (1 launch) ----
    wt_all_k<<<(114688 + TPB - 1) / TPB, TPB, 0, stream>>>(s1Wl, s1Wr, gW, s2Wl, s2Wr,
                                                           Wt1, Wt2, Wt3, deg);

    // ---- CSR build ----
    hist_k<<<(N_EDGES + TPB - 1) / TPB, TPB, 0, stream>>>(dst, deg);
    scan1_k<<<NCHUNK, 256, 0, stream>>>(deg, rowptr, bsum);
    scan2_k<<<1, 256, 0, stream>>>(bsum);
    scan3_k<<<NCHUNK, 256, 0, stream>>>(rowptr, bsum);
    fill_k<<<(N_EDGES + TPB - 1) / TPB, TPB, 0, stream>>>(src, dst, rowptr, deg, csr_src);

    // ---- SAGE1: Ab = bf16(relu([mean(x)|x] @ Wt1 + b)), K=40 (Kp=64) ----
    gm20_k<<<(N_NODES + 7) / 8, 256, 0, stream>>>(rowptr, csr_src, x, M20);
    gemm_mfma<1><<<dim3(2, MB), 256, 0, stream>>>(M20, 20, x, 20, Wt1, 64, s1b, Ab, 256);

    // ---- GAT: Cb = bf16(Ab @ Wt2) + fused att scores; fused gather -> Db ----
    gemm_mfma_bf<0, 0, 1><<<dim3(1, MB), 256, 0, stream>>>(
        Ab, 256, nullptr, 0, Wt2, 256, nullptr, Cb, 128,
        nullptr, nullptr, gas, gad, as_, ad_);
    gat_gather_bf<<<N_NODES / 8, 256, 0, stream>>>(rowptr, csr_src, Cb, as_, ad_, gb, Db);

    // ---- SAGE2 + fused classifier partials: pp[cb][n][5] ----
    gather_mean_bf<<<N_NODES / 8, 256, 0, stream>>>(rowptr, csr_src, Db, Mb);
    gemm_mfma_bf<1, 1, 0><<<dim3(2, MB), 256, 0, stream>>>(
        Mb, 128, Db, 128, Wt3, 256, s2b, nullptr, 256, clsW, pp,
        nullptr, nullptr, nullptr, nullptr);

    // ---- combine partials + bias ----
    combine_k<<<(N_NODES * 5 + TPB - 1) / TPB, TPB, 0, stream>>>(pp, clsb, out);
}